// Round 6
// baseline (501.460 us; speedup 1.0000x reference)
//
#include <hip/hip_runtime.h>

#define NNODES 65536
#define NEDGES 1048576
#define NCLS 40
#define BCAP 6144   // padded per-bucket capacity (mean 4096 + pad, sigma 64)

// fp8 gather buffer pre-scale: keeps |hws| in e4m3 normal range; folded into
// gemm epilogue (dis*32) and aggregate (dis/32) at zero cost.
#define FP8_SCALE 32.0f
#define FP8_INV   0.03125f

#define GRID 512    // 2 blocks/CU on 256 CUs -> all co-resident by construction
#define TPB  512

typedef unsigned int uint;
typedef __attribute__((ext_vector_type(8))) short bf16x8;
typedef __attribute__((ext_vector_type(4))) float f32x4;
typedef __attribute__((ext_vector_type(2))) float f32x2;

__device__ __forceinline__ uint pack_bf16x2(float a, float b) {
    uint ua = __builtin_bit_cast(uint, a);
    uint ub = __builtin_bit_cast(uint, b);
    ua += 0x7fff + ((ua >> 16) & 1);   // RNE to bf16
    ub += 0x7fff + ((ub >> 16) & 1);
    return (ua >> 16) | (ub & 0xffff0000u);
}
// value rounded to bf16, returned as float
__device__ __forceinline__ float tobf(float v) {
    uint u = __builtin_bit_cast(uint, v);
    u += 0x7fff + ((u >> 16) & 1);
    return __builtin_bit_cast(float, u & 0xffff0000u);
}
// fp8 pair -> 2 floats; low 16 bits of u hold the e4m3 pair (pre-shifted).
__device__ __forceinline__ f32x2 fp8_pair(uint u) {
    return __builtin_amdgcn_cvt_pk_f32_fp8((int)u, false);
}

struct Prm {
    const float* x;
    const int*   esrc;
    const int*   edst;
    const float* em;
    const float* w0;
    const float* b0;
    const float* convw;
    const float* convb;
    const float* ltw;
    const float* ltb;
    float*       out;
    uint*  hws8A;
    uint*  hws8B;
    uint*  WcombT;
    uint*  convwT;
    uint*  WcT8;
    int*   gcursor;
    uint*  binned;
    int*   row_beg;
    int*   row_end4;
    float* dis;
    int*   csr;
    int*   bar;
};

// ---- manual grid barrier (graph-capture safe; no cooperative launch) ----
// arrive: RELEASE agent-scope fetch_add (writes back this XCD's L2 to LLC).
// wait:   relaxed spin (no repeated cache invalidates) + one __threadfence()
//         acquire on exit (invalidates L1/L2 so reads see other XCDs' data).
// valve:  ~0.2s bounded spin -> visible wrong-answer instead of a hang.
__device__ __forceinline__ void gridbar(int* bar, int target, int t) {
    __syncthreads();
    if (t == 0) {
        __hip_atomic_fetch_add(bar, 1, __ATOMIC_RELEASE, __HIP_MEMORY_SCOPE_AGENT);
        int spins = 0;
        while (__hip_atomic_load(bar, __ATOMIC_RELAXED,
                                 __HIP_MEMORY_SCOPE_AGENT) < target) {
            __builtin_amdgcn_s_sleep(8);
            if (++spins > (1 << 20)) break;   // safety valve
        }
        __threadfence();
    }
    __syncthreads();
}

// ---------------- init: weight packs + counter zeroing (per replay) --------
__global__ __launch_bounds__(256) void init_pack(Prm p)
{
    int t = threadIdx.x;
    int b = blockIdx.x;
    for (int idx = b * 256 + t; idx < 30720; idx += 120 * 256) {
        if (idx < 24576) {
            // conv weights -> packed bf16 [l][o][fpair]
            int ip = idx & 63;
            int o = (idx >> 6) & 127;
            int l = idx >> 13;
            int i0 = ip * 2;
            float v0 = p.convw[l * 16384 + i0 * 128 + o];
            float v1 = p.convw[l * 16384 + (i0 + 1) * 128 + o];
            p.convwT[idx] = pack_bf16x2(v0, v1);
        } else {
            // WcT8 [96][64]: rows 0..47 bf16(W) (40->48 zero pad),
            // rows 48..95 residual bf16(W - bf16(W))
            int idx2 = idx - 24576;
            int part = (idx2 >= 3072) ? 1 : 0;
            int r = idx2 - part * 3072;
            int o = r >> 6;
            int ip = r & 63;
            float v0 = 0.f, v1 = 0.f;
            if (o < NCLS) {
                float w0v = p.ltw[o * 128 + ip * 2];
                float w1v = p.ltw[o * 128 + ip * 2 + 1];
                float h0 = tobf(w0v), h1 = tobf(w1v);
                if (part == 0) { v0 = h0; v1 = h1; }
                else { v0 = w0v - h0; v1 = w1v - h1; }
            }
            p.WcT8[idx2] = pack_bf16x2(v0, v1);
        }
    }
    if (b == 0) {
        p.gcursor[t] = 0;
        if (t < 16) p.bar[t] = 0;
    }
    if (b == 1 && t < 64) {   // zero sentinel rows of both fp8 buffers
        if (t < 32) p.hws8A[(size_t)NNODES * 32 + t] = 0u;
        else        p.hws8B[(size_t)NNODES * 32 + (t - 32)] = 0u;
    }
}

// ======== eighth-wave aggregation: 8 nodes per wave, 64-node tile ==========
__device__ __forceinline__ void aggregate_eighth(
    const uint* __restrict__ hws8_in, const int* __restrict__ row_beg,
    const int* __restrict__ row_end4, const int* __restrict__ csr,
    const float* __restrict__ dis, const float* __restrict__ bias,
    uint* __restrict__ hT, int rowBase, int wave, int lane)
{
    const int g = lane >> 3;
    const int s = lane & 7;
    const int nl = wave * 8 + g;
    const int n = rowBase + nl;
    const int beg = row_beg[n];
    const int end4 = row_end4[n];
    int mx = (end4 - beg) >> 2;
    mx = max(mx, __shfl_xor(mx, 8));
    mx = max(mx, __shfl_xor(mx, 16));
    mx = max(mx, __shfl_xor(mx, 32));

    uint4 su = *((const uint4*)(hws8_in + (size_t)n * 32) + s);
    f32x2 a[8];
    a[0] = fp8_pair(su.x); a[1] = fp8_pair(su.x >> 16);
    a[2] = fp8_pair(su.y); a[3] = fp8_pair(su.y >> 16);
    a[4] = fp8_pair(su.z); a[5] = fp8_pair(su.z >> 16);
    a[6] = fp8_pair(su.w); a[7] = fp8_pair(su.w >> 16);

#define ACC8(u) do { \
        a[0] += fp8_pair((u).x); a[1] += fp8_pair((u).x >> 16); \
        a[2] += fp8_pair((u).y); a[3] += fp8_pair((u).y >> 16); \
        a[4] += fp8_pair((u).z); a[5] += fp8_pair((u).z >> 16); \
        a[6] += fp8_pair((u).w); a[7] += fp8_pair((u).w >> 16); } while (0)

    int i = beg;
    for (int it = 0; it < mx; it += 2, i += 8) {
        int4 sA = *(const int4*)(csr + i);
        int4 sB = *(const int4*)(csr + i + 4);
        if (i >= end4) { sA.x = NNODES; sA.y = NNODES; sA.z = NNODES; sA.w = NNODES; }
        if (i + 4 >= end4) { sB.x = NNODES; sB.y = NNODES; sB.z = NNODES; sB.w = NNODES; }
        uint4 u0 = *((const uint4*)(hws8_in + (size_t)sA.x * 32) + s);
        uint4 u1 = *((const uint4*)(hws8_in + (size_t)sA.y * 32) + s);
        uint4 u2 = *((const uint4*)(hws8_in + (size_t)sA.z * 32) + s);
        uint4 u3 = *((const uint4*)(hws8_in + (size_t)sA.w * 32) + s);
        uint4 u4 = *((const uint4*)(hws8_in + (size_t)sB.x * 32) + s);
        uint4 u5 = *((const uint4*)(hws8_in + (size_t)sB.y * 32) + s);
        uint4 u6 = *((const uint4*)(hws8_in + (size_t)sB.z * 32) + s);
        uint4 u7 = *((const uint4*)(hws8_in + (size_t)sB.w * 32) + s);
        ACC8(u0); ACC8(u1); ACC8(u2); ACC8(u3);
        ACC8(u4); ACC8(u5); ACC8(u6); ACC8(u7);
    }
#undef ACC8

    const float d = dis[n] * FP8_INV;
    const float* bp = bias + s * 16;
    float4 b0 = *(const float4*)bp;
    float4 b1 = *(const float4*)(bp + 4);
    float4 b2 = *(const float4*)(bp + 8);
    float4 b3 = *(const float4*)(bp + 12);
    float o0  = fmaxf(fmaf(d, a[0].x, b0.x), 0.f);
    float o1  = fmaxf(fmaf(d, a[0].y, b0.y), 0.f);
    float o2  = fmaxf(fmaf(d, a[1].x, b0.z), 0.f);
    float o3  = fmaxf(fmaf(d, a[1].y, b0.w), 0.f);
    float o4  = fmaxf(fmaf(d, a[2].x, b1.x), 0.f);
    float o5  = fmaxf(fmaf(d, a[2].y, b1.y), 0.f);
    float o6  = fmaxf(fmaf(d, a[3].x, b1.z), 0.f);
    float o7  = fmaxf(fmaf(d, a[3].y, b1.w), 0.f);
    float o8  = fmaxf(fmaf(d, a[4].x, b2.x), 0.f);
    float o9  = fmaxf(fmaf(d, a[4].y, b2.y), 0.f);
    float o10 = fmaxf(fmaf(d, a[5].x, b2.z), 0.f);
    float o11 = fmaxf(fmaf(d, a[5].y, b2.w), 0.f);
    float o12 = fmaxf(fmaf(d, a[6].x, b3.x), 0.f);
    float o13 = fmaxf(fmaf(d, a[6].y, b3.y), 0.f);
    float o14 = fmaxf(fmaf(d, a[7].x, b3.z), 0.f);
    float o15 = fmaxf(fmaf(d, a[7].y, b3.w), 0.f);
    uint4 w0, w1;
    w0.x = pack_bf16x2(o0, o1);
    w0.y = pack_bf16x2(o2, o3);
    w0.z = pack_bf16x2(o4, o5);
    w0.w = pack_bf16x2(o6, o7);
    w1.x = pack_bf16x2(o8, o9);
    w1.y = pack_bf16x2(o10, o11);
    w1.z = pack_bf16x2(o12, o13);
    w1.w = pack_bf16x2(o14, o15);
    *(uint4*)&hT[nl * 68 + s * 8] = w0;
    *(uint4*)&hT[nl * 68 + s * 8 + 4] = w1;
}

// ---- LDS gemm for a 64-node tile: 8 waves = 2 M-strips x 4 N-quarters ----
__device__ __forceinline__ void gemm64(
    const uint* __restrict__ hT, const uint* __restrict__ BT,
    const float* __restrict__ dis, uint* __restrict__ out8,
    int rowBase, int wave, int lane)
{
    const int q = lane >> 4;
    const int l16 = lane & 15;
    const int mw = wave & 1;    // M-strip (32 rows)
    const int nw = wave >> 1;   // N-quarter (32 cols)

    f32x4 acc[2][2];
#pragma unroll
    for (int r = 0; r < 2; r++)
#pragma unroll
        for (int c = 0; c < 2; c++) {
            acc[r][c][0] = 0.f; acc[r][c][1] = 0.f;
            acc[r][c][2] = 0.f; acc[r][c][3] = 0.f;
        }

#pragma unroll
    for (int k0 = 0; k0 < 128; k0 += 32) {
        const int kp = (k0 >> 1) + q * 4;
        bf16x8 afrag[2];
#pragma unroll
        for (int r = 0; r < 2; r++) {
            uint4 u = *(const uint4*)&hT[(mw * 32 + r * 16 + l16) * 68 + kp];
            afrag[r] = __builtin_bit_cast(bf16x8, u);
        }
#pragma unroll
        for (int c = 0; c < 2; c++) {
            uint4 u = *(const uint4*)(BT +
                (size_t)(nw * 32 + c * 16 + l16) * 64 + kp);
            bf16x8 bfrag = __builtin_bit_cast(bf16x8, u);
#pragma unroll
            for (int r = 0; r < 2; r++)
                acc[r][c] = __builtin_amdgcn_mfma_f32_16x16x32_bf16(
                    afrag[r], bfrag, acc[r][c], 0, 0, 0);
        }
    }

#pragma unroll
    for (int r = 0; r < 2; r++) {
        int row0 = rowBase + mw * 32 + r * 16 + q * 4;
#pragma unroll
        for (int i = 0; i < 4; i++) {
            int row = row0 + i;
            float s32 = dis[row] * FP8_SCALE;
#pragma unroll
            for (int c = 0; c < 2; c++) {
                float v = acc[r][c][i] * s32;
                float w = __shfl_xor(v, 1);
                int us = __builtin_amdgcn_cvt_pk_fp8_f32(v, w, 0, false);
                uint partner = (uint)__shfl_xor(us, 2);
                if ((lane & 3) == 0) {
                    uint pk = ((uint)us & 0xffffu) | (partner << 16);
                    out8[(size_t)row * 32 + (nw * 2 + c) * 4 + (l16 >> 2)] = pk;
                }
            }
        }
    }
}

// =============================== mono-kernel ===============================
__global__ __launch_bounds__(TPB, 4) void gnn_mono(Prm p)
{
    __shared__ __align__(16) char smem[64 * 68 * 4];   // 17.4 KB arena
    const int bid = blockIdx.x;
    const int t = threadIdx.x;
    const int wave = t >> 6;
    const int lane = t & 63;

    // ---------------- P1: binned sort of edges by dst ----------------
    {
        int* lcnt = (int*)smem;
        int* lbase = lcnt + 256;
        int base = bid * 2048;
        if (t < 256) lcnt[t] = 0;
        __syncthreads();
        uint e[4];
#pragma unroll
        for (int k = 0; k < 4; k++) {
            int i = base + k * 512 + t;
            uint s = (uint)p.esrc[i];
            uint d = (uint)p.edst[i];
            e[k] = (d << 16) | s;
            atomicAdd(&lcnt[d >> 8], 1);
        }
        __syncthreads();
        if (t < 256) {
            lbase[t] = t * BCAP + atomicAdd(&p.gcursor[t], lcnt[t]);
            lcnt[t] = 0;
        }
        __syncthreads();
#pragma unroll
        for (int k = 0; k < 4; k++) {
            int b = e[k] >> 24;
            int r = atomicAdd(&lcnt[b], 1);
            p.binned[lbase[b] + r] = e[k];
        }
    }
    gridbar(p.bar, 1 * GRID, t);

    // ---------------- P2: csr_build (blocks 0-255) + wcomb (256-511) -------
    if (bid < 256) {
        int* cnt = (int*)smem;
        int* tmp = cnt + 256;
        int* fb = tmp + 256;
        int b = bid;
        int e0 = b * BCAP, e1 = e0 + p.gcursor[b];
        if (t < 256) cnt[t] = 0;
        __syncthreads();
        for (int i = e0 + t; i < e1; i += 512)
            atomicAdd(&cnt[(p.binned[i] >> 16) & 255], 1);
        __syncthreads();
        int v = 0, size4 = 0;
        if (t < 256) {
            v = cnt[t];
            size4 = (v + 3) & ~3;
            tmp[t] = size4;
        }
        __syncthreads();
        for (int off = 1; off < 256; off <<= 1) {
            int u = (t >= off && t < 256) ? tmp[t - off] : 0;
            __syncthreads();
            if (t < 256) tmp[t] += u;
            __syncthreads();
        }
        if (t < 256) {
            fb[t] = tmp[t] - size4;   // exclusive fine base (4-aligned sizes)
            int node = (b << 8) + t;
            int beg = e0 + fb[t];
            p.row_beg[node] = beg;
            p.row_end4[node] = beg + size4;
            p.dis[node] = rsqrtf((float)(v + 1));   // +1 self loop
            for (int q2 = v; q2 < size4; q2++) p.csr[beg + q2] = NNODES;
            cnt[t] = 0;
        }
        __syncthreads();
        for (int i = e0 + t; i < e1; i += 512) {
            uint e = p.binned[i];
            int d = (e >> 16) & 255;
            int r = atomicAdd(&cnt[d], 1);
            p.csr[e0 + fb[d] + r] = (int)(e & 0xffffu);
        }
    } else if (wave < 4) {
        // wcomb: WcombT[g] = (Wdyn[g] @ W1)^T, 16 f-cols per block
        int bb = bid - 256;
        const int g = bb >> 3;
        const int c = bb & 7;
        const int q = lane >> 4;
        const int l16 = lane & 15;
        const float* emg = p.em + g * 128;

        f32x4 acc[2];
#pragma unroll
        for (int r = 0; r < 2; r++) {
            acc[r][0] = 0.f; acc[r][1] = 0.f; acc[r][2] = 0.f; acc[r][3] = 0.f;
        }
        const int f = c * 16 + l16;
        const float wf = p.w0[f];

#pragma unroll
        for (int k0 = 0; k0 < 128; k0 += 32) {
            const int kf = k0 + q * 8;
            bf16x8 afrag[2];
#pragma unroll
            for (int r = 0; r < 2; r++) {
                uint4 u = *(const uint4*)(p.convwT +
                    (size_t)(wave * 32 + r * 16 + l16) * 64 + (kf >> 1));
                afrag[r] = __builtin_bit_cast(bf16x8, u);
            }
            float4 e0 = *(const float4*)(emg + kf);
            float4 e1 = *(const float4*)(emg + kf + 4);
            const float* bp = p.b0 + (size_t)f * 128 + kf;
            float4 bb0 = *(const float4*)bp;
            float4 bb1 = *(const float4*)(bp + 4);
            float v0 = fmaxf(fmaf(wf, e0.x, bb0.x), 0.f);
            float v1 = fmaxf(fmaf(wf, e0.y, bb0.y), 0.f);
            float v2 = fmaxf(fmaf(wf, e0.z, bb0.z), 0.f);
            float v3 = fmaxf(fmaf(wf, e0.w, bb0.w), 0.f);
            float v4 = fmaxf(fmaf(wf, e1.x, bb1.x), 0.f);
            float v5 = fmaxf(fmaf(wf, e1.y, bb1.y), 0.f);
            float v6 = fmaxf(fmaf(wf, e1.z, bb1.z), 0.f);
            float v7 = fmaxf(fmaf(wf, e1.w, bb1.w), 0.f);
            uint4 u;
            u.x = pack_bf16x2(v0, v1);
            u.y = pack_bf16x2(v2, v3);
            u.z = pack_bf16x2(v4, v5);
            u.w = pack_bf16x2(v6, v7);
            bf16x8 bfrag = __builtin_bit_cast(bf16x8, u);
#pragma unroll
            for (int r = 0; r < 2; r++)
                acc[r] = __builtin_amdgcn_mfma_f32_16x16x32_bf16(
                    afrag[r], bfrag, acc[r], 0, 0, 0);
        }

        uint* WTg = p.WcombT + (size_t)g * 8192;   // [o][fpair]
#pragma unroll
        for (int r = 0; r < 2; r++) {
            int o0 = wave * 32 + r * 16 + q * 4;
#pragma unroll
            for (int i = 0; i < 4; i++) {
                int o = o0 + i;
                float v = acc[r][i];
                float w = __shfl_xor(v, 1);
                uint pk = (lane & 1) ? pack_bf16x2(w, v) : pack_bf16x2(v, w);
                if (!(lane & 1))
                    WTg[(size_t)o * 64 + (uint)(f >> 1)] = pk;
            }
        }
    }
    gridbar(p.bar, 2 * GRID, t);

    // ---------------- P3: hws1 = (x @ Wcomb[g]) * dis * 32 -> fp8 ----------
    // 128-row tile per block, 8 waves = 4 M-strips x 2 N-halves
    {
        const int q = lane >> 4;
        const int l16 = lane & 15;
        const int rowBase = bid * 128;
        const int mw = wave & 3;
        const int nw = wave >> 2;
        const uint* Bp = p.WcombT + ((size_t)(rowBase >> 11) << 13);

        f32x4 acc[2][4];
#pragma unroll
        for (int r = 0; r < 2; r++)
#pragma unroll
            for (int c = 0; c < 4; c++) {
                acc[r][c][0] = 0.f; acc[r][c][1] = 0.f;
                acc[r][c][2] = 0.f; acc[r][c][3] = 0.f;
            }

        const int mBase = rowBase + mw * 32 + l16;

#pragma unroll
        for (int k0 = 0; k0 < 128; k0 += 32) {
            const int kf = k0 + q * 8;
            bf16x8 afrag[2];
#pragma unroll
            for (int r = 0; r < 2; r++) {
                const float* ap = p.x + (size_t)(mBase + r * 16) * 128 + kf;
                float4 a0 = *(const float4*)ap;
                float4 a1 = *(const float4*)(ap + 4);
                uint4 u;
                u.x = pack_bf16x2(a0.x, a0.y);
                u.y = pack_bf16x2(a0.z, a0.w);
                u.z = pack_bf16x2(a1.x, a1.y);
                u.w = pack_bf16x2(a1.z, a1.w);
                afrag[r] = __builtin_bit_cast(bf16x8, u);
            }
#pragma unroll
            for (int c = 0; c < 4; c++) {
                uint4 u = *(const uint4*)(Bp +
                    (size_t)(nw * 64 + c * 16 + l16) * 64 + (kf >> 1));
                bf16x8 bfrag = __builtin_bit_cast(bf16x8, u);
#pragma unroll
                for (int r = 0; r < 2; r++)
                    acc[r][c] = __builtin_amdgcn_mfma_f32_16x16x32_bf16(
                        afrag[r], bfrag, acc[r][c], 0, 0, 0);
            }
        }

#pragma unroll
        for (int r = 0; r < 2; r++) {
            int row0 = rowBase + mw * 32 + r * 16 + q * 4;
#pragma unroll
            for (int i = 0; i < 4; i++) {
                int row = row0 + i;
                float s32 = p.dis[row] * FP8_SCALE;
#pragma unroll
                for (int c = 0; c < 4; c++) {
                    float v = acc[r][c][i] * s32;
                    float w = __shfl_xor(v, 1);
                    int us = __builtin_amdgcn_cvt_pk_fp8_f32(v, w, 0, false);
                    uint partner = (uint)__shfl_xor(us, 2);
                    if ((lane & 3) == 0) {
                        uint pk = ((uint)us & 0xffffu) | (partner << 16);
                        p.hws8A[(size_t)row * 32 + nw * 16 + c * 4 + (l16 >> 2)] = pk;
                    }
                }
            }
        }
    }
    gridbar(p.bar, 3 * GRID, t);

    // ---------------- P4/P5: conv layers 1 and 2 (agg -> LDS -> gemm) ------
    uint* hT = (uint*)smem;
#pragma unroll 1
    for (int layer = 0; layer < 2; layer++) {
        const uint* in8 = layer ? p.hws8B : p.hws8A;
        uint* out8 = layer ? p.hws8A : p.hws8B;
        const uint* BT = p.convwT + (size_t)(layer + 1) * 8192;
        const float* bias = p.convb + layer * 128;
#pragma unroll 1
        for (int vt = bid; vt < NNODES / 64; vt += GRID) {
            const int rowBase = vt * 64;
            aggregate_eighth(in8, p.row_beg, p.row_end4, p.csr, p.dis, bias,
                             hT, rowBase, wave, lane);
            __syncthreads();
            gemm64(hT, BT, p.dis, out8, rowBase, wave, lane);
            __syncthreads();
        }
        gridbar(p.bar, (4 + layer) * GRID, t);
    }

    // ---------------- P6: layer 3 agg -> MFMA logits + log_softmax ---------
#pragma unroll 1
    for (int vt = bid; vt < NNODES / 64; vt += GRID) {
        const int rowBase = vt * 64;
        aggregate_eighth(p.hws8A, p.row_beg, p.row_end4, p.csr, p.dis,
                         p.convb + 2 * 128, hT, rowBase, wave, lane);
        __syncthreads();

        if (wave < 4) {
            const int q = lane >> 4;
            const int l16 = lane & 15;

            f32x4 acc[3];
#pragma unroll
            for (int c = 0; c < 3; c++) {
                acc[c][0] = 0.f; acc[c][1] = 0.f; acc[c][2] = 0.f; acc[c][3] = 0.f;
            }

#pragma unroll
            for (int k0 = 0; k0 < 128; k0 += 32) {
                const int kp = (k0 >> 1) + q * 4;
                uint4 ua = *(const uint4*)&hT[(wave * 16 + l16) * 68 + kp];
                bf16x8 af = __builtin_bit_cast(bf16x8, ua);
#pragma unroll
                for (int tile = 0; tile < 3; tile++) {
                    uint4 uh = *(const uint4*)(p.WcT8 +
                        (size_t)(tile * 16 + l16) * 64 + kp);
                    uint4 ul = *(const uint4*)(p.WcT8 +
                        (size_t)(48 + tile * 16 + l16) * 64 + kp);
                    acc[tile] = __builtin_amdgcn_mfma_f32_16x16x32_bf16(
                        af, __builtin_bit_cast(bf16x8, uh), acc[tile], 0, 0, 0);
                    acc[tile] = __builtin_amdgcn_mfma_f32_16x16x32_bf16(
                        af, __builtin_bit_cast(bf16x8, ul), acc[tile], 0, 0, 0);
                }
            }

            const float bt0 = p.ltb[l16];
            const float bt1 = p.ltb[16 + l16];
            const float bt2 = (l16 < 8) ? p.ltb[32 + l16] : 0.f;

#pragma unroll
            for (int i = 0; i < 4; i++) {
                const int node = rowBase + wave * 16 + q * 4 + i;
                float g0 = acc[0][i] + bt0;
                float g1 = acc[1][i] + bt1;
                float g2 = (l16 < 8) ? (acc[2][i] + bt2) : -1e30f;
                float m = fmaxf(fmaxf(g0, g1), g2);
                for (int off = 1; off < 16; off <<= 1)
                    m = fmaxf(m, __shfl_xor(m, off));
                float sum = expf(g0 - m) + expf(g1 - m) +
                            ((l16 < 8) ? expf(g2 - m) : 0.f);
                for (int off = 1; off < 16; off <<= 1)
                    sum += __shfl_xor(sum, off);
                float lse = m + logf(sum);
                float* on = p.out + (size_t)node * NCLS;
                on[l16] = g0 - lse;
                on[16 + l16] = g1 - lse;
                if (l16 < 8) on[32 + l16] = g2 - lse;
            }
        }
        __syncthreads();
    }
}

extern "C" void kernel_launch(void* const* d_in, const int* in_sizes, int n_in,
                              void* d_out, int out_size, void* d_ws, size_t ws_size,
                              hipStream_t stream)
{
    Prm p;
    p.x     = (const float*)d_in[0];
    const int* ei = (const int*)d_in[1];   // [2, E] int32
    p.em    = (const float*)d_in[2];
    // d_in[3] = ptr (uniform partitions; unused)
    p.w0    = (const float*)d_in[4];
    p.b0    = (const float*)d_in[5];
    p.convw = (const float*)d_in[6]; // [3,128,128]
    p.convb = (const float*)d_in[7]; // [3,128]
    p.ltw   = (const float*)d_in[8]; // [40,128]
    p.ltb   = (const float*)d_in[9]; // [40]
    p.out   = (float*)d_out;
    p.esrc  = ei;
    p.edst  = ei + NEDGES;

    char* ws = (char*)d_ws;
    size_t off = 0;
    auto alloc = [&](size_t bytes) -> void* {
        void* q = ws + off;
        off += (bytes + 255) & ~(size_t)255;
        return q;
    };
    p.hws8A    = (uint*)alloc((size_t)(NNODES + 1) * 32 * 4);  // fp8 + sentinel
    p.hws8B    = (uint*)alloc((size_t)(NNODES + 1) * 32 * 4);
    p.WcombT   = (uint*)alloc((size_t)32 * 128 * 64 * 4);
    p.convwT   = (uint*)alloc((size_t)3 * 128 * 64 * 4);
    p.WcT8     = (uint*)alloc((size_t)96 * 64 * 4);
    p.gcursor  = (int*)alloc(256 * 4);
    p.binned   = (uint*)alloc((size_t)256 * BCAP * 4);
    p.row_beg  = (int*)alloc((size_t)NNODES * 4);
    p.row_end4 = (int*)alloc((size_t)NNODES * 4);
    p.dis      = (float*)alloc((size_t)NNODES * 4);
    p.csr      = (int*)alloc((size_t)256 * BCAP * 4);
    p.bar      = (int*)alloc(256 * 4);

    init_pack<<<120, 256, 0, stream>>>(p);
    gnn_mono<<<GRID, TPB, 0, stream>>>(p);
}

// Round 7
// 234.710 us; speedup vs baseline: 2.1365x; 2.1365x over previous
//
#include <hip/hip_runtime.h>

#define NNODES 65536
#define NEDGES 1048576
#define HDIM 128
#define NCLS 40
#define BCAP 6144   // padded per-bucket capacity (mean 4096+pad<=768, sigma 64)

// fp8 gather buffer pre-scale: keeps |hws| in e4m3 normal range; folded into
// gemm epilogue (dis*32) and aggregate (dis/32) at zero cost.
#define FP8_SCALE 32.0f
#define FP8_INV   0.03125f

typedef unsigned int uint;
typedef __attribute__((ext_vector_type(8))) short bf16x8;
typedef __attribute__((ext_vector_type(4))) float f32x4;
typedef __attribute__((ext_vector_type(2))) float f32x2;

__device__ __forceinline__ uint pack_bf16x2(float a, float b) {
    uint ua = __builtin_bit_cast(uint, a);
    uint ub = __builtin_bit_cast(uint, b);
    ua += 0x7fff + ((ua >> 16) & 1);   // RNE to bf16
    ub += 0x7fff + ((ub >> 16) & 1);
    return (ua >> 16) | (ub & 0xffff0000u);
}
// value rounded to bf16, returned as float
__device__ __forceinline__ float tobf(float v) {
    uint u = __builtin_bit_cast(uint, v);
    u += 0x7fff + ((u >> 16) & 1);
    return __builtin_bit_cast(float, u & 0xffff0000u);
}
// fp8 pair -> 2 floats; low 16 bits of u hold the e4m3 pair (pre-shifted).
__device__ __forceinline__ f32x2 fp8_pair(uint u) {
    return __builtin_amdgcn_cvt_pk_f32_fp8((int)u, false);
}

// ======== merged: binned edge sort (blocks 0-255) + weight packs (256+) ====
// gcursor is zeroed by a hipMemsetAsync before this launch.
// blocks 256..351: conv weights -> packed bf16 [l][o][fpair] (24576 uints)
// blocks 352..375: WcT8 [96][64]: rows 0..47 = bf16(W) (classes 40->48 zero
// pad), rows 48..95 = bf16(W - bf16(W)) residual; 2-term split keeps MFMA
// logits numerically equal to fp32-W (~2^-17 rel err).
__global__ __launch_bounds__(256) void scatter_pack(
    const int* __restrict__ src, const int* __restrict__ dst,
    int* __restrict__ gcursor, uint* __restrict__ binned,
    const float* __restrict__ cw, uint* __restrict__ WT,
    const float* __restrict__ ltw, uint* __restrict__ WcT8)
{
    __shared__ int lcnt[256];
    __shared__ int lbase[256];
    int t = threadIdx.x;
    int blk = blockIdx.x;
    if (blk < 256) {
        int base = blk * 4096;
        lcnt[t] = 0;
        __syncthreads();
        uint e[16];
#pragma unroll
        for (int k = 0; k < 16; k++) {
            int i = base + k * 256 + t;
            uint s = (uint)src[i];
            uint d = (uint)dst[i];
            e[k] = (d << 16) | s;
            atomicAdd(&lcnt[d >> 8], 1);
        }
        __syncthreads();
        lbase[t] = t * BCAP + atomicAdd(&gcursor[t], lcnt[t]);
        lcnt[t] = 0;
        __syncthreads();
#pragma unroll
        for (int k = 0; k < 16; k++) {
            int b = e[k] >> 24;
            int r = atomicAdd(&lcnt[b], 1);
            binned[lbase[b] + r] = e[k];
        }
    } else if (blk < 352) {
        int idx = (blk - 256) * 256 + t;     // [0, 24576)
        int ip = idx & 63;
        int o = (idx >> 6) & 127;
        int l = idx >> 13;
        int i0 = ip * 2;
        float v0 = cw[l * 16384 + i0 * 128 + o];
        float v1 = cw[l * 16384 + (i0 + 1) * 128 + o];
        WT[idx] = pack_bf16x2(v0, v1);
    } else {
        int idx2 = (blk - 352) * 256 + t;    // [0, 6144)
        int part = (idx2 >= 3072) ? 1 : 0;
        int r = idx2 - part * 3072;
        int o = r >> 6;                      // class 0..47
        int ip = r & 63;
        float v0 = 0.f, v1 = 0.f;
        if (o < NCLS) {
            float w0v = ltw[o * 128 + ip * 2];
            float w1v = ltw[o * 128 + ip * 2 + 1];
            float h0 = tobf(w0v), h1 = tobf(w1v);
            if (part == 0) { v0 = h0; v1 = h1; }
            else { v0 = w0v - h0; v1 = w1v - h1; }
        }
        WcT8[idx2] = pack_bf16x2(v0, v1);
    }
}

// ---------------- merged: csr_build (blocks 0-255) + wcomb (blocks 256-511) --
// csr rows padded to multiple of 4; padding slots hold sentinel NNODES
// (a zero hws row) so the aggregate can use int4 index loads.
__global__ __launch_bounds__(256) void prep_kernel(
    const uint* __restrict__ binned, const int* __restrict__ gcursor,
    int* __restrict__ row_beg, int* __restrict__ row_end4,
    float* __restrict__ dis, int* __restrict__ csr,
    const float* __restrict__ w0, const float* __restrict__ em,
    const float* __restrict__ b0, const uint* __restrict__ convwT0,
    uint* __restrict__ WT)
{
    __shared__ int cnt[256];
    __shared__ int tmp[256];
    __shared__ int fb[256];
    const int t = threadIdx.x;

    if (blockIdx.x < 256) {
        // ---- csr_build ----
        int b = blockIdx.x;
        int e0 = b * BCAP, e1 = e0 + gcursor[b];
        cnt[t] = 0;
        __syncthreads();
        for (int i = e0 + t; i < e1; i += 256)
            atomicAdd(&cnt[(binned[i] >> 16) & 255], 1);
        __syncthreads();
        int v = cnt[t];
        int size4 = (v + 3) & ~3;
        tmp[t] = size4;
        __syncthreads();
        for (int off = 1; off < 256; off <<= 1) {
            int u = (t >= off) ? tmp[t - off] : 0;
            __syncthreads();
            tmp[t] += u;
            __syncthreads();
        }
        fb[t] = tmp[t] - size4;   // exclusive fine base (4-aligned sizes)
        int node = (b << 8) + t;
        int beg = e0 + fb[t];
        row_beg[node] = beg;
        row_end4[node] = beg + size4;
        dis[node] = rsqrtf((float)(v + 1));   // +1 self loop
        for (int p = v; p < size4; p++) csr[beg + p] = NNODES;  // sentinel
        cnt[t] = 0;
        __syncthreads();
        for (int i = e0 + t; i < e1; i += 256) {
            uint e = binned[i];
            int d = (e >> 16) & 255;
            int r = atomicAdd(&cnt[d], 1);
            csr[e0 + fb[d] + r] = (int)(e & 0xffffu);
        }
    } else {
        // ---- wcomb: WcombT[g] = (Wdyn[g] @ W1)^T, 16 f-cols per block ----
        int bb = blockIdx.x - 256;
        const int g = bb >> 3;
        const int c = bb & 7;
        const int wave = t >> 6;
        const int lane = t & 63;
        const int q = lane >> 4;
        const int l16 = lane & 15;
        const float* emg = em + g * 128;

        f32x4 acc[2];
#pragma unroll
        for (int r = 0; r < 2; r++) {
            acc[r][0] = 0.f; acc[r][1] = 0.f; acc[r][2] = 0.f; acc[r][3] = 0.f;
        }
        const int f = c * 16 + l16;
        const float wf = w0[f];

#pragma unroll
        for (int k0 = 0; k0 < 128; k0 += 32) {
            const int kf = k0 + q * 8;
            bf16x8 afrag[2];
#pragma unroll
            for (int r = 0; r < 2; r++) {
                uint4 u = *(const uint4*)(convwT0 +
                    (size_t)(wave * 32 + r * 16 + l16) * 64 + (kf >> 1));
                afrag[r] = __builtin_bit_cast(bf16x8, u);
            }
            float4 e0 = *(const float4*)(emg + kf);
            float4 e1 = *(const float4*)(emg + kf + 4);
            const float* bp = b0 + (size_t)f * 128 + kf;
            float4 bb0 = *(const float4*)bp;
            float4 bb1 = *(const float4*)(bp + 4);
            float v0 = fmaxf(fmaf(wf, e0.x, bb0.x), 0.f);
            float v1 = fmaxf(fmaf(wf, e0.y, bb0.y), 0.f);
            float v2 = fmaxf(fmaf(wf, e0.z, bb0.z), 0.f);
            float v3 = fmaxf(fmaf(wf, e0.w, bb0.w), 0.f);
            float v4 = fmaxf(fmaf(wf, e1.x, bb1.x), 0.f);
            float v5 = fmaxf(fmaf(wf, e1.y, bb1.y), 0.f);
            float v6 = fmaxf(fmaf(wf, e1.z, bb1.z), 0.f);
            float v7 = fmaxf(fmaf(wf, e1.w, bb1.w), 0.f);
            uint4 u;
            u.x = pack_bf16x2(v0, v1);
            u.y = pack_bf16x2(v2, v3);
            u.z = pack_bf16x2(v4, v5);
            u.w = pack_bf16x2(v6, v7);
            bf16x8 bfrag = __builtin_bit_cast(bf16x8, u);
#pragma unroll
            for (int r = 0; r < 2; r++)
                acc[r] = __builtin_amdgcn_mfma_f32_16x16x32_bf16(
                    afrag[r], bfrag, acc[r], 0, 0, 0);
        }

        uint* WTg = WT + (size_t)g * 8192;   // [o][fpair]
#pragma unroll
        for (int r = 0; r < 2; r++) {
            int o0 = wave * 32 + r * 16 + q * 4;
#pragma unroll
            for (int i = 0; i < 4; i++) {
                int o = o0 + i;
                float v = acc[r][i];
                float w = __shfl_xor(v, 1);
                uint p = (lane & 1) ? pack_bf16x2(w, v) : pack_bf16x2(v, w);
                if (!(lane & 1))
                    WTg[(size_t)o * 64 + (uint)(f >> 1)] = p;
            }
        }
    }
}

// ---- fp8 epilogue: store (acc*dis*32) as e4m3, 4 feats/uint ----
__device__ __forceinline__ void store_fp8_row(
    uint* __restrict__ Cp8, int row, float s32, const f32x4* accRC,
    int lane, int l16, int i)
{
#pragma unroll
    for (int c = 0; c < 8; c++) {
        float v = accRC[c][i] * s32;
        float w = __shfl_xor(v, 1);
        int us = __builtin_amdgcn_cvt_pk_fp8_f32(v, w, 0, false);
        uint partner = (uint)__shfl_xor(us, 2);
        if ((lane & 3) == 0) {
            uint p = ((uint)us & 0xffffu) | (partner << 16);
            Cp8[(size_t)row * 32 + c * 4 + (l16 >> 2)] = p;
        }
    }
}

// ---------------- MFMA GEMM (fp32 A): hws8 = (A @ B) * dis * 32 -> fp8 ----
__global__ __launch_bounds__(256) void gemm_mfma(
    const float* __restrict__ A, const uint* __restrict__ BT,
    uint* __restrict__ Cp8, const float* __restrict__ dis, int perGroup)
{
    const int t = threadIdx.x;
    const int wave = t >> 6;
    const int lane = t & 63;
    const int q = lane >> 4;
    const int l16 = lane & 15;
    const int rowBase = blockIdx.x * 128;
    const uint* Bp = perGroup ? BT + ((size_t)(rowBase >> 11) << 13) : BT;

    if (blockIdx.x == 0 && t < 32)
        Cp8[(size_t)NNODES * 32 + t] = 0u;   // zero sentinel row

    f32x4 acc[2][8];
#pragma unroll
    for (int r = 0; r < 2; r++)
#pragma unroll
        for (int c = 0; c < 8; c++) {
            acc[r][c][0] = 0.f; acc[r][c][1] = 0.f;
            acc[r][c][2] = 0.f; acc[r][c][3] = 0.f;
        }

    const int mBase = rowBase + wave * 32 + l16;

#pragma unroll
    for (int k0 = 0; k0 < 128; k0 += 32) {
        const int kf = k0 + q * 8;
        bf16x8 afrag[2];
#pragma unroll
        for (int r = 0; r < 2; r++) {
            const float* ap = A + (size_t)(mBase + r * 16) * 128 + kf;
            float4 a0 = *(const float4*)ap;
            float4 a1 = *(const float4*)(ap + 4);
            uint4 u;
            u.x = pack_bf16x2(a0.x, a0.y);
            u.y = pack_bf16x2(a0.z, a0.w);
            u.z = pack_bf16x2(a1.x, a1.y);
            u.w = pack_bf16x2(a1.z, a1.w);
            afrag[r] = __builtin_bit_cast(bf16x8, u);
        }
#pragma unroll
        for (int c = 0; c < 8; c++) {
            uint4 u = *(const uint4*)(Bp + (size_t)(c * 16 + l16) * 64 + (kf >> 1));
            bf16x8 bfrag = __builtin_bit_cast(bf16x8, u);
#pragma unroll
            for (int r = 0; r < 2; r++)
                acc[r][c] = __builtin_amdgcn_mfma_f32_16x16x32_bf16(
                    afrag[r], bfrag, acc[r][c], 0, 0, 0);
        }
    }

#pragma unroll
    for (int r = 0; r < 2; r++) {
        int row0 = rowBase + wave * 32 + r * 16 + q * 4;
#pragma unroll
        for (int i = 0; i < 4; i++) {
            int row = row0 + i;
            float s32 = dis[row] * FP8_SCALE;
            store_fp8_row(Cp8, row, s32, acc[r], lane, l16, i);
        }
    }
}

// ======== quarter-wave aggregation: 4 nodes per wave concurrently ==========
// Lane (q = lane>>4, s = lane&15): node group-of-4 member q, features 8s..8s+7
// (one uint2 = 8B per row). One gather instruction fetches 4 rows (512 B);
// 8 in flight per inner iteration. Per-quarter degree divergence handled by
// masked int4 csr loads (sentinel row NNODES is zeroed).
__device__ __forceinline__ void aggregate_quarter(
    const uint* __restrict__ hws8_in, const int* __restrict__ row_beg,
    const int* __restrict__ row_end4, const int* __restrict__ csr,
    const float* __restrict__ dis, const float* __restrict__ bias,
    uint* __restrict__ hT, int rowBase, int wave, int lane)
{
    const int q = lane >> 4;
    const int s = lane & 15;
    const float4 bv0 = *(const float4*)(bias + s * 8);
    const float4 bv1 = *(const float4*)(bias + s * 8 + 4);
#pragma unroll
    for (int j = 0; j < 4; j++) {
        const int nl = wave * 16 + j * 4 + q;
        const int n = rowBase + nl;
        const int beg = row_beg[n];
        const int end4 = row_end4[n];
        int mx = (end4 - beg) >> 2;
        mx = max(mx, __shfl_xor(mx, 16));
        mx = max(mx, __shfl_xor(mx, 32));
        uint2 su = *((const uint2*)(hws8_in + (size_t)n * 32) + s);
        f32x2 a0 = fp8_pair(su.x), a1 = fp8_pair(su.x >> 16);
        f32x2 a2 = fp8_pair(su.y), a3 = fp8_pair(su.y >> 16);
        f32x2 b0 = {0.f, 0.f}, b1 = {0.f, 0.f};
        f32x2 b2 = {0.f, 0.f}, b3 = {0.f, 0.f};
        int i = beg;
        for (int it = 0; it < mx; it += 2, i += 8) {
            int4 sA = *(const int4*)(csr + i);
            int4 sB = *(const int4*)(csr + i + 4);
            if (i >= end4) { sA.x = NNODES; sA.y = NNODES; sA.z = NNODES; sA.w = NNODES; }
            if (i + 4 >= end4) { sB.x = NNODES; sB.y = NNODES; sB.z = NNODES; sB.w = NNODES; }
            uint2 u0 = *((const uint2*)(hws8_in + (size_t)sA.x * 32) + s);
            uint2 u1 = *((const uint2*)(hws8_in + (size_t)sA.y * 32) + s);
            uint2 u2 = *((const uint2*)(hws8_in + (size_t)sA.z * 32) + s);
            uint2 u3 = *((const uint2*)(hws8_in + (size_t)sA.w * 32) + s);
            uint2 u4 = *((const uint2*)(hws8_in + (size_t)sB.x * 32) + s);
            uint2 u5 = *((const uint2*)(hws8_in + (size_t)sB.y * 32) + s);
            uint2 u6 = *((const uint2*)(hws8_in + (size_t)sB.z * 32) + s);
            uint2 u7 = *((const uint2*)(hws8_in + (size_t)sB.w * 32) + s);
            a0 += fp8_pair(u0.x); a1 += fp8_pair(u0.x >> 16);
            a2 += fp8_pair(u0.y); a3 += fp8_pair(u0.y >> 16);
            b0 += fp8_pair(u1.x); b1 += fp8_pair(u1.x >> 16);
            b2 += fp8_pair(u1.y); b3 += fp8_pair(u1.y >> 16);
            a0 += fp8_pair(u2.x); a1 += fp8_pair(u2.x >> 16);
            a2 += fp8_pair(u2.y); a3 += fp8_pair(u2.y >> 16);
            b0 += fp8_pair(u3.x); b1 += fp8_pair(u3.x >> 16);
            b2 += fp8_pair(u3.y); b3 += fp8_pair(u3.y >> 16);
            a0 += fp8_pair(u4.x); a1 += fp8_pair(u4.x >> 16);
            a2 += fp8_pair(u4.y); a3 += fp8_pair(u4.y >> 16);
            b0 += fp8_pair(u5.x); b1 += fp8_pair(u5.x >> 16);
            b2 += fp8_pair(u5.y); b3 += fp8_pair(u5.y >> 16);
            a0 += fp8_pair(u6.x); a1 += fp8_pair(u6.x >> 16);
            a2 += fp8_pair(u6.y); a3 += fp8_pair(u6.y >> 16);
            b0 += fp8_pair(u7.x); b1 += fp8_pair(u7.x >> 16);
            b2 += fp8_pair(u7.y); b3 += fp8_pair(u7.y >> 16);
        }
        a0 += b0; a1 += b1; a2 += b2; a3 += b3;
        const float d = dis[n] * FP8_INV;
        float o0 = fmaxf(fmaf(d, a0.x, bv0.x), 0.f);
        float o1 = fmaxf(fmaf(d, a0.y, bv0.y), 0.f);
        float o2 = fmaxf(fmaf(d, a1.x, bv0.z), 0.f);
        float o3 = fmaxf(fmaf(d, a1.y, bv0.w), 0.f);
        float o4 = fmaxf(fmaf(d, a2.x, bv1.x), 0.f);
        float o5 = fmaxf(fmaf(d, a2.y, bv1.y), 0.f);
        float o6 = fmaxf(fmaf(d, a3.x, bv1.z), 0.f);
        float o7 = fmaxf(fmaf(d, a3.y, bv1.w), 0.f);
        uint4 w;
        w.x = pack_bf16x2(o0, o1);
        w.y = pack_bf16x2(o2, o3);
        w.z = pack_bf16x2(o4, o5);
        w.w = pack_bf16x2(o6, o7);
        *(uint4*)&hT[nl * 68 + s * 4] = w;
    }
}

// ============ FUSED: aggregate(fp8 in) -> LDS bf16 tile -> GEMM -> fp8 out ==
__global__ __launch_bounds__(512) void agg_gemm_kernel(
    const uint* __restrict__ hws8_in, const int* __restrict__ row_beg,
    const int* __restrict__ row_end4, const int* __restrict__ csr,
    const float* __restrict__ dis, const float* __restrict__ bias,
    const uint* __restrict__ BT, uint* __restrict__ out8)
{
    __shared__ uint hT[128 * 68];   // 34.8 KB
    const int t = threadIdx.x;
    const int wave = t >> 6;
    const int lane = t & 63;
    const int rowBase = blockIdx.x * 128;

    if (blockIdx.x == 0 && t < 32)
        out8[(size_t)NNODES * 32 + t] = 0u;   // zero sentinel row of OUTPUT

    aggregate_quarter(hws8_in, row_beg, row_end4, csr, dis, bias,
                      hT, rowBase, wave, lane);
    __syncthreads();

    // ---------------- phase 2: GEMM from LDS ----------------
    const int q = lane >> 4;
    const int l16 = lane & 15;
    const int mw = wave & 3;    // M-strip (32 rows)
    const int nw = wave >> 2;   // N-half (64 cols)

    f32x4 acc[2][4];
#pragma unroll
    for (int r = 0; r < 2; r++)
#pragma unroll
        for (int c = 0; c < 4; c++) {
            acc[r][c][0] = 0.f; acc[r][c][1] = 0.f;
            acc[r][c][2] = 0.f; acc[r][c][3] = 0.f;
        }

#pragma unroll
    for (int k0 = 0; k0 < 128; k0 += 32) {
        const int kp = (k0 >> 1) + q * 4;
        bf16x8 afrag[2];
#pragma unroll
        for (int r = 0; r < 2; r++) {
            uint4 u = *(const uint4*)&hT[(mw * 32 + r * 16 + l16) * 68 + kp];
            afrag[r] = __builtin_bit_cast(bf16x8, u);
        }
#pragma unroll
        for (int c = 0; c < 4; c++) {
            uint4 u = *(const uint4*)(BT +
                (size_t)(nw * 64 + c * 16 + l16) * 64 + kp);
            bf16x8 bfrag = __builtin_bit_cast(bf16x8, u);
#pragma unroll
            for (int r = 0; r < 2; r++)
                acc[r][c] = __builtin_amdgcn_mfma_f32_16x16x32_bf16(
                    afrag[r], bfrag, acc[r][c], 0, 0, 0);
        }
    }

#pragma unroll
    for (int r = 0; r < 2; r++) {
        int row0 = rowBase + mw * 32 + r * 16 + q * 4;
#pragma unroll
        for (int i = 0; i < 4; i++) {
            int row = row0 + i;
            float s32 = dis[row] * FP8_SCALE;
#pragma unroll
            for (int c = 0; c < 4; c++) {
                float v = acc[r][c][i] * s32;
                float w = __shfl_xor(v, 1);
                int us = __builtin_amdgcn_cvt_pk_fp8_f32(v, w, 0, false);
                uint partner = (uint)__shfl_xor(us, 2);
                if ((lane & 3) == 0) {
                    uint p = ((uint)us & 0xffffu) | (partner << 16);
                    out8[(size_t)row * 32 + (nw * 4 + c) * 4 + (l16 >> 2)] = p;
                }
            }
        }
    }
}

// ============ FUSED: aggregate(fp8 in) -> LDS bf16 tile -> MFMA logits ======
// Phase 2: per wave 16 nodes; C tiles 16x16x32 vs WcT8 (hi+lo bf16 split).
// C layout: node = q*4+i, class col = tile*16+l16 (tile2 valid for l16<8).
__global__ __launch_bounds__(512) void agg_logits_kernel(
    const uint* __restrict__ hws8_in, const int* __restrict__ row_beg,
    const int* __restrict__ row_end4, const int* __restrict__ csr,
    const float* __restrict__ dis, const float* __restrict__ bias,
    const uint* __restrict__ WcT8, const float* __restrict__ bc,
    float* __restrict__ out)
{
    __shared__ uint hT[128 * 68];       // 34.8 KB
    const int t = threadIdx.x;
    const int wave = t >> 6;
    const int lane = t & 63;
    const int rowBase = blockIdx.x * 128;

    aggregate_quarter(hws8_in, row_beg, row_end4, csr, dis, bias,
                      hT, rowBase, wave, lane);
    __syncthreads();

    // ---------------- phase 2: logits via MFMA + log_softmax ---------------
    const int q = lane >> 4;
    const int l16 = lane & 15;

    f32x4 acc[3];
#pragma unroll
    for (int c = 0; c < 3; c++) {
        acc[c][0] = 0.f; acc[c][1] = 0.f; acc[c][2] = 0.f; acc[c][3] = 0.f;
    }

#pragma unroll
    for (int k0 = 0; k0 < 128; k0 += 32) {
        const int kp = (k0 >> 1) + q * 4;
        uint4 ua = *(const uint4*)&hT[(wave * 16 + l16) * 68 + kp];
        bf16x8 af = __builtin_bit_cast(bf16x8, ua);
#pragma unroll
        for (int tile = 0; tile < 3; tile++) {
            uint4 uh = *(const uint4*)(WcT8 + (size_t)(tile * 16 + l16) * 64 + kp);
            uint4 ul = *(const uint4*)(WcT8 + (size_t)(48 + tile * 16 + l16) * 64 + kp);
            acc[tile] = __builtin_amdgcn_mfma_f32_16x16x32_bf16(
                af, __builtin_bit_cast(bf16x8, uh), acc[tile], 0, 0, 0);
            acc[tile] = __builtin_amdgcn_mfma_f32_16x16x32_bf16(
                af, __builtin_bit_cast(bf16x8, ul), acc[tile], 0, 0, 0);
        }
    }

    const float bt0 = bc[l16];
    const float bt1 = bc[16 + l16];
    const float bt2 = (l16 < 8) ? bc[32 + l16] : 0.f;

#pragma unroll
    for (int i = 0; i < 4; i++) {
        const int node = rowBase + wave * 16 + q * 4 + i;
        float g0 = acc[0][i] + bt0;
        float g1 = acc[1][i] + bt1;
        float g2 = (l16 < 8) ? (acc[2][i] + bt2) : -1e30f;
        float m = fmaxf(fmaxf(g0, g1), g2);
        for (int off = 1; off < 16; off <<= 1) m = fmaxf(m, __shfl_xor(m, off));
        float sum = expf(g0 - m) + expf(g1 - m) + ((l16 < 8) ? expf(g2 - m) : 0.f);
        for (int off = 1; off < 16; off <<= 1) sum += __shfl_xor(sum, off);
        float lse = m + logf(sum);
        float* on = out + (size_t)node * NCLS;
        on[l16] = g0 - lse;
        on[16 + l16] = g1 - lse;
        if (l16 < 8) on[32 + l16] = g2 - lse;
    }
}

extern "C" void kernel_launch(void* const* d_in, const int* in_sizes, int n_in,
                              void* d_out, int out_size, void* d_ws, size_t ws_size,
                              hipStream_t stream)
{
    const float* x     = (const float*)d_in[0];
    const int*   ei    = (const int*)d_in[1];   // [2, E] int32
    const float* em    = (const float*)d_in[2];
    // d_in[3] = ptr (uniform partitions; unused)
    const float* w0    = (const float*)d_in[4];
    const float* b0    = (const float*)d_in[5];
    const float* convw = (const float*)d_in[6]; // [3,128,128]
    const float* convb = (const float*)d_in[7]; // [3,128]
    const float* ltw   = (const float*)d_in[8]; // [40,128]
    const float* ltb   = (const float*)d_in[9]; // [40]
    float* out = (float*)d_out;

    char* ws = (char*)d_ws;
    size_t off = 0;
    auto alloc = [&](size_t bytes) -> void* {
        void* p = ws + off;
        off += (bytes + 255) & ~(size_t)255;
        return p;
    };
    uint*  hws8A    = (uint*)alloc((size_t)(NNODES + 1) * 32 * 4);  // fp8 + sentinel
    uint*  hws8B    = (uint*)alloc((size_t)(NNODES + 1) * 32 * 4);
    uint*  WcombT   = (uint*)alloc((size_t)32 * 128 * 64 * 4);
    uint*  convwT   = (uint*)alloc((size_t)3 * 128 * 64 * 4);
    uint*  WcT8     = (uint*)alloc((size_t)96 * 64 * 4);
    int*   gcursor  = (int*)alloc(256 * 4);
    uint*  binned   = (uint*)alloc((size_t)256 * BCAP * 4);
    int*   row_beg  = (int*)alloc((size_t)NNODES * 4);
    int*   row_end4 = (int*)alloc((size_t)NNODES * 4);
    float* dis      = (float*)alloc((size_t)NNODES * 4);
    int*   csr      = (int*)alloc((size_t)256 * BCAP * 4);

    const int* esrc = ei;
    const int* edst = ei + NEDGES;

    hipMemsetAsync(gcursor, 0, 256 * 4, stream);
    scatter_pack<<<376, 256, 0, stream>>>(esrc, edst, gcursor, binned,
                                          convw, convwT, ltw, WcT8);
    prep_kernel<<<512, 256, 0, stream>>>(binned, gcursor, row_beg, row_end4, dis,
                                         csr, w0, em, b0, convwT, WcombT);

    // hws1 = (x @ Wcomb[g]) * dis * 32  -> fp8
    gemm_mfma<<<NNODES / 128, 256, 0, stream>>>(x, WcombT, hws8A, dis, 1);

    // layer 1: fused aggregate(fp8) -> LDS bf16 -> GEMM W2 -> fp8
    agg_gemm_kernel<<<NNODES / 128, 512, 0, stream>>>(
        hws8A, row_beg, row_end4, csr, dis, convb + 0 * 128,
        convwT + (size_t)1 * 8192, hws8B);
    // layer 2
    agg_gemm_kernel<<<NNODES / 128, 512, 0, stream>>>(
        hws8B, row_beg, row_end4, csr, dis, convb + 1 * 128,
        convwT + (size_t)2 * 8192, hws8A);
    // layer 3: fused aggregate -> MFMA logits + log_softmax
    agg_logits_kernel<<<NNODES / 128, 512, 0, stream>>>(
        hws8A, row_beg, row_end4, csr, dis, convb + 2 * 128, WcT8, ltb, out);
}